// Round 1
// baseline (1576.439 us; speedup 1.0000x reference)
//
#include <hip/hip_runtime.h>
#include <hip/hip_bf16.h>

constexpr int N_NODES = 100000;
constexpr int N_EDGES = 1600000;
constexpr int D = 64;

// ---------------------------------------------------------------------------
// Kernel 1: edge scatter-add.  16 threads per edge, float4 per thread.
// h_agg[dst[e]][:] += features[src[e]][:]
// ---------------------------------------------------------------------------
__global__ void gcn_scatter_kernel(const float* __restrict__ feat,
                                   const int* __restrict__ src,
                                   const int* __restrict__ dst,
                                   float* __restrict__ hagg) {
    int t = blockIdx.x * blockDim.x + threadIdx.x;
    int e = t >> 4;            // edge index
    if (e >= N_EDGES) return;
    int c = (t & 15) << 2;     // feature chunk offset: 0,4,...,60

    int s = src[e];
    int d = dst[e];

    const float4 v = *reinterpret_cast<const float4*>(feat + (size_t)s * D + c);
    float* p = hagg + (size_t)d * D + c;
    atomicAdd(p + 0, v.x);
    atomicAdd(p + 1, v.y);
    atomicAdd(p + 2, v.z);
    atomicAdd(p + 3, v.w);
}

// ---------------------------------------------------------------------------
// Kernel 2: out = relu(h_agg @ W^T + b)
// One wave per node.  W staged transposed in LDS: Wt[k][j] = W[j][k] so that
// lane j reading Wt[k*64+j] is a 2-way (free) bank pattern; hrow[k] reads are
// same-address broadcasts.
// ---------------------------------------------------------------------------
__global__ void gcn_linear_kernel(const float* __restrict__ hagg,
                                  const float* __restrict__ W,
                                  const float* __restrict__ b,
                                  float* __restrict__ out) {
    __shared__ float Wt[D * D];      // 16 KiB
    __shared__ float hrow[4][D];     // one row per wave

    const int tid = threadIdx.x;     // 256 threads = 4 waves
    const int w   = tid >> 6;        // wave id in block
    const int j   = tid & 63;        // output column / lane

    // Stage W transposed: Wt[k*64 + j] = W[j*64 + k]
    #pragma unroll
    for (int i = 0; i < D * D / 256; ++i) {
        int idx = tid + i * 256;         // coalesced read of W
        int jj = idx >> 6;               // row of W
        int kk = idx & 63;               // col of W
        Wt[kk * D + jj] = W[idx];
    }
    __syncthreads();

    const float bj = b[j];

    // 4 nodes per block (one per wave), grid-stride
    for (int node = blockIdx.x * 4 + w; node < N_NODES; node += gridDim.x * 4) {
        hrow[w][j] = hagg[(size_t)node * D + j];   // coalesced, wave-local
        // wave-synchronous: same wave wrote, same wave reads (lockstep on CDNA)
        float acc = bj;
        #pragma unroll
        for (int k = 0; k < D; ++k) {
            acc = fmaf(hrow[w][k], Wt[k * D + j], acc);
        }
        out[(size_t)node * D + j] = fmaxf(acc, 0.0f);
    }
}

extern "C" void kernel_launch(void* const* d_in, const int* in_sizes, int n_in,
                              void* d_out, int out_size, void* d_ws, size_t ws_size,
                              hipStream_t stream) {
    const float* feat = (const float*)d_in[0];
    const int*   src  = (const int*)d_in[1];
    const int*   dst  = (const int*)d_in[2];
    const float* W    = (const float*)d_in[3];
    const float* b    = (const float*)d_in[4];
    float* out = (float*)d_out;

    float* hagg = (float*)d_ws;                       // N_NODES * D floats = 25.6 MB
    const size_t hagg_bytes = (size_t)N_NODES * D * sizeof(float);

    // zero the accumulator (graph-capture safe)
    hipMemsetAsync(hagg, 0, hagg_bytes, stream);

    // scatter-add over edges: 16 threads/edge
    {
        int total = N_EDGES * 16;
        int block = 256;
        int grid = (total + block - 1) / block;
        gcn_scatter_kernel<<<grid, block, 0, stream>>>(feat, src, dst, hagg);
    }

    // linear + bias + relu: one wave per node, 4 waves per block
    {
        int block = 256;
        int grid = (N_NODES + 3) / 4;   // 25000 blocks
        gcn_linear_kernel<<<grid, block, 0, stream>>>(hagg, W, b, out);
    }
}

// Round 2
// 294.308 us; speedup vs baseline: 5.3564x; 5.3564x over previous
//
#include <hip/hip_runtime.h>
#include <hip/hip_bf16.h>

constexpr int N_NODES = 100000;
constexpr int N_EDGES = 1600000;
constexpr int D = 64;
constexpr int NB = (N_NODES + 255) / 256;   // 391 scan blocks

// ---------------------------------------------------------------------------
// Phase 1: histogram of dst -> deg[]
// ---------------------------------------------------------------------------
__global__ void hist_kernel(const int* __restrict__ dst, int* __restrict__ deg) {
    for (int e = blockIdx.x * blockDim.x + threadIdx.x; e < N_EDGES;
         e += gridDim.x * blockDim.x) {
        atomicAdd(&deg[dst[e]], 1);
    }
}

// ---------------------------------------------------------------------------
// Phase 2a: per-block sums of deg (256 nodes per block)
// ---------------------------------------------------------------------------
__global__ void block_sum_kernel(const int* __restrict__ deg, int* __restrict__ bsum) {
    const int b = blockIdx.x, t = threadIdx.x;
    const int v = b * 256 + t;
    int x = (v < N_NODES) ? deg[v] : 0;
    #pragma unroll
    for (int o = 1; o < 64; o <<= 1) x += __shfl_down(x, o);
    __shared__ int ws_[4];
    if ((t & 63) == 0) ws_[t >> 6] = x;
    __syncthreads();
    if (t == 0) bsum[b] = ws_[0] + ws_[1] + ws_[2] + ws_[3];
}

// ---------------------------------------------------------------------------
// Phase 2b: scan of block sums (one block, 512 threads; NB=391 fits)
// ---------------------------------------------------------------------------
__global__ void scan_bsum_kernel(const int* __restrict__ bsum, int* __restrict__ bpref,
                                 int* __restrict__ offN) {
    __shared__ int sh[512];
    const int t = threadIdx.x;
    const int x = (t < NB) ? bsum[t] : 0;
    sh[t] = x;
    __syncthreads();
    for (int o = 1; o < 512; o <<= 1) {
        int y = (t >= o) ? sh[t - o] : 0;
        __syncthreads();
        sh[t] += y;
        __syncthreads();
    }
    if (t < NB) bpref[t] = sh[t] - x;       // exclusive
    if (t == NB - 1) *offN = sh[t];         // total = N_EDGES
}

// ---------------------------------------------------------------------------
// Phase 2c: final exclusive scan -> off[], cursor[]
// ---------------------------------------------------------------------------
__global__ void scan_final_kernel(const int* __restrict__ deg, const int* __restrict__ bpref,
                                  int* __restrict__ off, int* __restrict__ cursor) {
    __shared__ int sh[256];
    const int b = blockIdx.x, t = threadIdx.x;
    const int v = b * 256 + t;
    const int x = (v < N_NODES) ? deg[v] : 0;
    sh[t] = x;
    __syncthreads();
    for (int o = 1; o < 256; o <<= 1) {
        int y = (t >= o) ? sh[t - o] : 0;
        __syncthreads();
        sh[t] += y;
        __syncthreads();
    }
    if (v < N_NODES) {
        const int e = bpref[b] + sh[t] - x;  // global exclusive prefix
        off[v] = e;
        cursor[v] = e;
    }
}

// ---------------------------------------------------------------------------
// Phase 3: scatter src ids into CSR-by-dst order
// ---------------------------------------------------------------------------
__global__ void scatter_edges_kernel(const int* __restrict__ src, const int* __restrict__ dst,
                                     int* __restrict__ cursor, int* __restrict__ sorted) {
    for (int e = blockIdx.x * blockDim.x + threadIdx.x; e < N_EDGES;
         e += gridDim.x * blockDim.x) {
        const int d = dst[e];
        const int pos = atomicAdd(&cursor[d], 1);
        sorted[pos] = src[e];
    }
}

// ---------------------------------------------------------------------------
// Phase 4: fused gather + linear + bias + relu.
// One wave per node (4 waves/block, grid-stride). Lane j owns feature col j.
// W row j lives in 16 float4 registers per lane; h broadcast via uniform
// ds_read_b128 from the wave's LDS row.
// ---------------------------------------------------------------------------
__global__ void gather_linear_kernel(const float* __restrict__ feat,
                                     const int* __restrict__ off,
                                     const int* __restrict__ sorted,
                                     const float* __restrict__ W,
                                     const float* __restrict__ b,
                                     float* __restrict__ out) {
    const int tid = threadIdx.x;
    const int w = tid >> 6;
    const int j = tid & 63;

    // W row j -> registers (16 KB total per wave, L1/L2-hot after first wave)
    float4 wr[16];
    #pragma unroll
    for (int q = 0; q < 16; ++q)
        wr[q] = *reinterpret_cast<const float4*>(W + j * D + q * 4);
    const float bj = b[j];

    __shared__ float hrow[4][D];

    for (int v = blockIdx.x * 4 + w; v < N_NODES; v += gridDim.x * 4) {
        const int beg = off[v];
        const int end = off[v + 1];
        float h = 0.0f;

        for (int base = beg; base < end; base += 64) {
            int cnt = end - base;
            if (cnt > 64) cnt = 64;
            int eid = 0;
            if (j < cnt) eid = sorted[base + j];   // coalesced chunk load

            int i = 0;
            for (; i + 4 <= cnt; i += 4) {
                const int s0 = __shfl(eid, i);
                const int s1 = __shfl(eid, i + 1);
                const int s2 = __shfl(eid, i + 2);
                const int s3 = __shfl(eid, i + 3);
                const float v0 = feat[(size_t)s0 * D + j];   // 256B coalesced each
                const float v1 = feat[(size_t)s1 * D + j];
                const float v2 = feat[(size_t)s2 * D + j];
                const float v3 = feat[(size_t)s3 * D + j];
                h += v0; h += v1; h += v2; h += v3;
            }
            for (; i < cnt; ++i) {
                const int s = __shfl(eid, i);
                h += feat[(size_t)s * D + j];
            }
        }

        hrow[w][j] = h;                      // wave-local LDS, no barrier needed
        float acc = bj;
        #pragma unroll
        for (int q = 0; q < 16; ++q) {
            const float4 hv = *reinterpret_cast<const float4*>(&hrow[w][q * 4]); // broadcast
            acc = fmaf(hv.x, wr[q].x, acc);
            acc = fmaf(hv.y, wr[q].y, acc);
            acc = fmaf(hv.z, wr[q].z, acc);
            acc = fmaf(hv.w, wr[q].w, acc);
        }
        out[(size_t)v * D + j] = fmaxf(acc, 0.0f);
    }
}

extern "C" void kernel_launch(void* const* d_in, const int* in_sizes, int n_in,
                              void* d_out, int out_size, void* d_ws, size_t ws_size,
                              hipStream_t stream) {
    const float* feat = (const float*)d_in[0];
    const int*   src  = (const int*)d_in[1];
    const int*   dst  = (const int*)d_in[2];
    const float* W    = (const float*)d_in[3];
    const float* b    = (const float*)d_in[4];
    float* out = (float*)d_out;

    // workspace layout (ints)
    int* ws     = (int*)d_ws;
    int* deg    = ws;                        // N_NODES
    int* off    = deg + N_NODES;             // N_NODES + 1
    int* cursor = off + N_NODES + 1;         // N_NODES
    int* bsum   = cursor + N_NODES;          // 512 (NB=391 used)
    int* bpref  = bsum + 512;                // 512
    int* sorted = bpref + 512;               // N_EDGES

    hipMemsetAsync(deg, 0, (size_t)N_NODES * sizeof(int), stream);

    hist_kernel<<<2048, 256, 0, stream>>>(dst, deg);

    block_sum_kernel<<<NB, 256, 0, stream>>>(deg, bsum);
    scan_bsum_kernel<<<1, 512, 0, stream>>>(bsum, bpref, off + N_NODES);
    scan_final_kernel<<<NB, 256, 0, stream>>>(deg, bpref, off, cursor);

    scatter_edges_kernel<<<2048, 256, 0, stream>>>(src, dst, cursor, sorted);

    gather_linear_kernel<<<2048, 256, 0, stream>>>(feat, off, sorted, W, b, out);
}